// Round 6
// baseline (1459.205 us; speedup 1.0000x reference)
//
#include <hip/hip_runtime.h>
#include <hip/hip_bf16.h>

#define N_ATOMS 25000
#define N_PAIRS 500000
#define DEPTH 4

typedef _Float16 f16x8 __attribute__((ext_vector_type(8)));
typedef float f32x16 __attribute__((ext_vector_type(16)));
typedef unsigned short u16;

__device__ __forceinline__ float tanh_fast(float x) {
    float e = __expf(2.0f * x);
    return 1.0f - 2.0f * __builtin_amdgcn_rcpf(e + 1.0f);
}

__device__ __forceinline__ void split_h(float x, u16& hi, u16& lo) {
    _Float16 h = (_Float16)x;
    _Float16 l = (_Float16)(x - (float)h);
    hi = *(u16*)&h;
    lo = *(u16*)&l;
}

// ---------------- prep: split weights to hi/lo fp16, fragment-major images
// img1 per depth: [hl][ntw][ks(8)][l(64)][j(8)]        = 16384 u16
// img2 per depth: [hl][ntw][t(4)][ks(4)][l][j]         = 32768 u16  (cols permuted: n=4*ch+t)
// imgab per depth: [stage][hl][ntw][ks(4)][l][j]       = 16384 u16
__global__ __launch_bounds__(256)
void prep_kernel(const float* __restrict__ piW1, const float* __restrict__ piW2,
                 const float* __restrict__ iiW1, const float* __restrict__ iiW2,
                 u16* __restrict__ img1, u16* __restrict__ img2, u16* __restrict__ imgab) {
    int gid = blockIdx.x * 256 + threadIdx.x;
    int d = gid >> 15, e = gid & 32767;
    u16 hi, lo;
    if (e < 8192) {                 // W1 [k=128][n=64]
        int k = e >> 6, n = e & 63;
        split_h(piW1[d * 8192 + e], hi, lo);
        int ntw = n >> 5, colb = n & 31;
        int ks = k >> 4, lh = (k >> 3) & 1, j = k & 7;
        int off = ((ntw * 8 + ks) * 64 + lh * 32 + colb) * 8 + j;
        img1[d * 16384 + 0 * 8192 + off] = hi;
        img1[d * 16384 + 1 * 8192 + off] = lo;
    } else if (e < 24576) {         // W2 [k=64][n=256], permuted n = 4*ch + t
        int s = e - 8192;
        int k = s >> 8, n = s & 255;
        split_h(piW2[d * 16384 + s], hi, lo);
        int ch = n >> 2, t = n & 3;
        int ntw = ch >> 5, colb = ch & 31;
        int ks = k >> 4, lh = (k >> 3) & 1, j = k & 7;
        int off = (((ntw * 4 + t) * 4 + ks) * 64 + lh * 32 + colb) * 8 + j;
        img2[d * 32768 + 0 * 16384 + off] = hi;
        img2[d * 32768 + 1 * 16384 + off] = lo;
    } else {                        // Wa (stage0) / Wb (stage1), [k=64][n=64]
        int stage = (e < 28672) ? 0 : 1;
        int s = e - (stage ? 28672 : 24576);
        int k = s >> 6, n = s & 63;
        float x = stage ? iiW2[d * 4096 + s] : iiW1[d * 4096 + s];
        split_h(x, hi, lo);
        int ntw = n >> 5, colb = n & 31;
        int ks = k >> 4, lh = (k >> 3) & 1, j = k & 7;
        int off = ((ntw * 4 + ks) * 64 + lh * 32 + colb) * 8 + j;
        imgab[d * 16384 + (stage * 2 + 0) * 4096 + off] = hi;
        imgab[d * 16384 + (stage * 2 + 1) * 4096 + off] = lo;
    }
}

__global__ __launch_bounds__(256)
void prep_b2(const float* __restrict__ piB2, float* __restrict__ b2p) {
    int d = blockIdx.x, n = threadIdx.x;
    int ch = n >> 2, t = n & 3;
    int np = (ch >> 5) * 128 + t * 32 + (ch & 31);
    b2p[d * 256 + np] = piB2[d * 256 + n];
}

// ---------------- atom-level MLP (fp32 VALU), h stored split fp16
template <int K, bool IS_D0>
__global__ __launch_bounds__(256)
void atom_mlp(const float* __restrict__ p_in,
              const float* __restrict__ W1, const float* __restrict__ b1,
              const float* __restrict__ W2, const float* __restrict__ b2,
              const float* __restrict__ res0_w,
              _Float16* __restrict__ h_hi, _Float16* __restrict__ h_lo,
              float* __restrict__ acc_out) {
    __shared__ float sP[4][64];
    __shared__ float sH[4][64];
    int tid = threadIdx.x;
    int al = tid >> 6, c = tid & 63;
    int a = blockIdx.x * 4 + al;
    if (c < K) sP[al][c] = p_in[a * K + c];
    __syncthreads();
    float s = b1[c];
#pragma unroll
    for (int k = 0; k < K; ++k) s += sP[al][k] * W1[k * 64 + c];
    float t1 = tanh_fast(s);
    float r;
    if (IS_D0) {
        r = 0.f;
#pragma unroll
        for (int k = 0; k < 16; ++k) r += sP[al][k] * res0_w[k * 64 + c];
    } else {
        r = sP[al][c];
    }
    acc_out[a * 64 + c] = r;
    sH[al][c] = t1;
    __syncthreads();
    float s2 = b2[c];
#pragma unroll
    for (int k = 0; k < 64; ++k) s2 += sH[al][k] * W2[k * 64 + c];
    float hv = tanh_fast(s2);
    _Float16 hb = (_Float16)hv;
    h_hi[a * 64 + c] = hb;
    h_lo[a * 64 + c] = (_Float16)(hv - (float)hb);
}

// ---------------- output head (fp32)
__global__ __launch_bounds__(256)
void out_kernel(const float* __restrict__ p,
                const float* __restrict__ W1, const float* __restrict__ b1,
                const float* __restrict__ W2, const float* __restrict__ b2,
                const float* __restrict__ wo,
                float* __restrict__ out, int store) {
    __shared__ float sP[4][64];
    __shared__ float sH[4][64];
    int tid = threadIdx.x;
    int al = tid >> 6, c = tid & 63;
    int a = blockIdx.x * 4 + al;
    sP[al][c] = p[a * 64 + c];
    __syncthreads();
    float s = b1[c];
#pragma unroll
    for (int k = 0; k < 64; ++k) s += sP[al][k] * W1[k * 64 + c];
    sH[al][c] = tanh_fast(s);
    __syncthreads();
    float s2 = b2[c];
#pragma unroll
    for (int k = 0; k < 64; ++k) s2 += sH[al][k] * W2[k * 64 + c];
    float v = tanh_fast(s2) * wo[c];
#pragma unroll
    for (int off = 32; off > 0; off >>= 1) v += __shfl_down(v, off, 64);
    if (c == 0) {
        if (store) out[a] = v;
        else out[a] += v;
    }
}

// ---------------- fused pair pipeline: fp16 MFMA, low-LDS, 2 blocks/CU, swizzled frags
#define MFMA __builtin_amdgcn_mfma_f32_32x32x16_f16

__global__ __launch_bounds__(512, 4)
void pair_kernel(const _Float16* __restrict__ hhi,
                 const _Float16* __restrict__ hlo,
                 const int* __restrict__ ind2,
                 const float* __restrict__ basis,
                 const u16* __restrict__ img1,
                 const u16* __restrict__ img2,
                 const u16* __restrict__ imgab,
                 const float* __restrict__ piB1,
                 const float* __restrict__ b2p,
                 float* __restrict__ accp) {
    __shared__ __attribute__((aligned(16))) _Float16 sW2hi[16384];  // 32 KB
    __shared__ __attribute__((aligned(16))) _Float16 sPing[8192];   // 16 KB
    __shared__ __attribute__((aligned(16))) _Float16 sInter[8192];  // 16 KB
    __shared__ float sBas[128 * 4];                                 //  2 KB
    __shared__ int sIdx[128];                                       // 0.5 KB
    // total 66.5 KB -> 2 blocks/CU, 16 waves/CU

    const int tid = threadIdx.x;
    for (int i = tid; i < 2048; i += 512) ((uint4*)sW2hi)[i] = ((const uint4*)img2)[i];

    const int l = tid & 63;
    const int w = tid >> 6;
    const int mt = w >> 1, ntw = w & 1;
    const int col = l & 31, kg = l >> 5;
    const int ch = ntw * 32 + col;
    const int chks = ch >> 4, chlh = (ch >> 3) & 1, chj = ch & 7;
    // C-store: elem = (mt*4+chks)*512 + chlh*256 + ((Lc ^ rr2)<<3) + chj ; addr = cbase ^ (Lc<<3)
    const int rr2 = (chks * 2 + chlh) ^ (kg << 2);
    const int cbase = (mt * 4 + chks) * 512 + chlh * 256 + (rr2 << 3) + chj;
    // A-read: elem(ks) = (mt*4+ks)*512 + abase ^ (ks<<4)
    const int abase = kg * 256 + (((l & 31) ^ kg) << 3);
    const int mrow = mt * 32 + col;   // this lane's pair row within tile

    const float b1v = piB1[ch];
    float b2v[4];
#pragma unroll
    for (int t = 0; t < 4; ++t) b2v[t] = b2p[ntw * 128 + t * 32 + col];

    const int nTiles = (N_PAIRS + 127) >> 7;
    __syncthreads();

    // prefetch pair indices for first tile
    int pc0 = min(blockIdx.x * 128 + mrow, N_PAIRS - 1);
    int2 ij = *(const int2*)(ind2 + 2 * pc0);

    for (int tile = blockIdx.x; tile < nTiles; tile += gridDim.x) {
        const int base = tile << 7;

        // ---- G1: stage basis/idx; direct A-gathers; [128x128]@[128x64]+b1, tanh -> sPing
        if (tid < 128) {
            int pc = min(base + tid, N_PAIRS - 1);
            *(float4*)&sBas[tid * 4] = ((const float4*)basis)[pc];
            sIdx[tid] = ind2[2 * pc];
        }
        {
            f16x8 ai[4], aj[4], al4[4];
            const _Float16* hri = hhi + ij.x * 64 + kg * 8;
            const _Float16* hrj = hhi + ij.y * 64 + kg * 8;
            const _Float16* hrl = hlo + ij.x * 64 + kg * 8;
#pragma unroll
            for (int ks = 0; ks < 4; ++ks) {
                ai[ks] = *(const f16x8*)(hri + ks * 16);
                aj[ks] = *(const f16x8*)(hrj + ks * 16);
                al4[ks] = *(const f16x8*)(hrl + ks * 16);
            }
            f32x16 acc = {};
            const u16* w1h = img1 + ntw * 4096 + l * 8;
            const u16* w1l = img1 + 8192 + ntw * 4096 + l * 8;
#pragma unroll
            for (int ks = 0; ks < 4; ++ks) {
                f16x8 whA = *(const f16x8*)(w1h + ks * 512);
                f16x8 whB = *(const f16x8*)(w1h + (ks + 4) * 512);
                f16x8 wlA = *(const f16x8*)(w1l + ks * 512);
                f16x8 wlB = *(const f16x8*)(w1l + (ks + 4) * 512);
                acc = MFMA(ai[ks], whA, acc, 0, 0, 0);
                acc = MFMA(aj[ks], whB, acc, 0, 0, 0);
                acc = MFMA(ai[ks], wlA, acc, 0, 0, 0);
                acc = MFMA(aj[ks], wlB, acc, 0, 0, 0);
                acc = MFMA(al4[ks], whA, acc, 0, 0, 0);   // h_i lo correction
            }
#pragma unroll
            for (int r = 0; r < 16; ++r) {
                const int Lc = (r & 3) + 8 * (r >> 2);
                sPing[cbase ^ (Lc << 3)] = (_Float16)tanh_fast(acc[r] + b1v);
            }
        }
        __syncthreads();

        // ---- G2: [128x64]@[64x256]+b2 (hi LDS + lo global), tanh, basis contraction -> sInter
        {
            float inter[16];
#pragma unroll
            for (int r = 0; r < 16; ++r) inter[r] = 0.f;
#pragma unroll
            for (int tp = 0; tp < 2; ++tp) {
                f32x16 acc0 = {}, acc1 = {};
                const int t0 = tp * 2, t1 = tp * 2 + 1;
#pragma unroll
                for (int ks = 0; ks < 4; ++ks) {
                    f16x8 a = *(const f16x8*)(sPing + ((mt * 4 + ks) * 512 + (abase ^ (ks << 4))));
                    const _Float16* bh0 = sW2hi + ((ntw * 4 + t0) * 4 + ks) * 512 + l * 8;
                    const _Float16* bh1 = sW2hi + ((ntw * 4 + t1) * 4 + ks) * 512 + l * 8;
                    const u16* bl0 = img2 + 16384 + ((ntw * 4 + t0) * 4 + ks) * 512 + l * 8;
                    const u16* bl1 = img2 + 16384 + ((ntw * 4 + t1) * 4 + ks) * 512 + l * 8;
                    acc0 = MFMA(a, *(const f16x8*)bh0, acc0, 0, 0, 0);
                    acc0 = MFMA(a, *(const f16x8*)bl0, acc0, 0, 0, 0);
                    acc1 = MFMA(a, *(const f16x8*)bh1, acc1, 0, 0, 0);
                    acc1 = MFMA(a, *(const f16x8*)bl1, acc1, 0, 0, 0);
                }
#pragma unroll
                for (int r = 0; r < 16; ++r) {
                    const int Lc = (r & 3) + 8 * (r >> 2);
                    const int row = mt * 32 + Lc + 4 * kg;
                    float4 bas = *(const float4*)&sBas[row * 4];
                    float bA = tp ? bas.z : bas.x;
                    float bB = tp ? bas.w : bas.y;
                    inter[r] += tanh_fast(acc0[r] + b2v[t0]) * bA
                              + tanh_fast(acc1[r] + b2v[t1]) * bB;
                }
            }
#pragma unroll
            for (int r = 0; r < 16; ++r) {
                const int Lc = (r & 3) + 8 * (r >> 2);
                sInter[cbase ^ (Lc << 3)] = (_Float16)inter[r];
            }
        }
        __syncthreads();

        // ---- G3: inter @ ii_w1 (hi), tanh -> sPing
        {
            f32x16 acc = {};
#pragma unroll
            for (int ks = 0; ks < 4; ++ks) {
                f16x8 a = *(const f16x8*)(sInter + ((mt * 4 + ks) * 512 + (abase ^ (ks << 4))));
                f16x8 fwa = *(const f16x8*)(imgab + ntw * 2048 + ks * 512 + l * 8);
                acc = MFMA(a, fwa, acc, 0, 0, 0);
            }
#pragma unroll
            for (int r = 0; r < 16; ++r) {
                const int Lc = (r & 3) + 8 * (r >> 2);
                sPing[cbase ^ (Lc << 3)] = (_Float16)tanh_fast(acc[r]);
            }
        }
        __syncthreads();

        // ---- G4: @ ii_w2 (hi), tanh, atomic scatter; prefetch next ij
        {
            f32x16 acc = {};
#pragma unroll
            for (int ks = 0; ks < 4; ++ks) {
                f16x8 a = *(const f16x8*)(sPing + ((mt * 4 + ks) * 512 + (abase ^ (ks << 4))));
                f16x8 fwb = *(const f16x8*)(imgab + 8192 + ntw * 2048 + ks * 512 + l * 8);
                acc = MFMA(a, fwb, acc, 0, 0, 0);
            }
            int pcn = min((tile + gridDim.x) * 128 + mrow, N_PAIRS - 1);
            ij = *(const int2*)(ind2 + 2 * pcn);   // prefetch for next tile
#pragma unroll
            for (int r = 0; r < 16; ++r) {
                const int Lc = (r & 3) + 8 * (r >> 2);
                const int lrow = Lc + 4 * kg;
                const int p = base + mt * 32 + lrow;
                if (p < N_PAIRS)
                    atomicAdd(&accp[sIdx[mt * 32 + lrow] * 64 + ch], tanh_fast(acc[r]));
            }
        }
        __syncthreads();
    }
}

extern "C" void kernel_launch(void* const* d_in, const int* in_sizes, int n_in,
                              void* d_out, int out_size, void* d_ws, size_t ws_size,
                              hipStream_t stream) {
    const int* ind2 = (const int*)d_in[0];
    const float* prop = (const float*)d_in[1];
    const float* basis = (const float*)d_in[2];
    const float* pp0_w1 = (const float*)d_in[3];
    const float* pp0_b1 = (const float*)d_in[4];
    const float* pp_w1 = (const float*)d_in[5];
    const float* pp_b1 = (const float*)d_in[6];
    const float* pp_w2 = (const float*)d_in[7];
    const float* pp_b2 = (const float*)d_in[8];
    const float* pi_w1 = (const float*)d_in[9];
    const float* pi_b1 = (const float*)d_in[10];
    const float* pi_w2 = (const float*)d_in[11];
    const float* pi_b2 = (const float*)d_in[12];
    const float* ii_w1 = (const float*)d_in[13];
    const float* ii_w2 = (const float*)d_in[14];
    const float* res0_w = (const float*)d_in[15];
    const float* out_w1 = (const float*)d_in[16];
    const float* out_b1 = (const float*)d_in[17];
    const float* out_w2 = (const float*)d_in[18];
    const float* out_b2 = (const float*)d_in[19];
    const float* out_wo = (const float*)d_in[20];
    float* out = (float*)d_out;

    float* B0 = (float*)d_ws;
    float* B1 = B0 + N_ATOMS * 64;
    _Float16* Hhi = (_Float16*)(B1 + N_ATOMS * 64);
    _Float16* Hlo = Hhi + N_ATOMS * 64;
    u16* img1 = (u16*)(Hlo + N_ATOMS * 64);
    u16* img2 = img1 + 4 * 16384;
    u16* imgab = img2 + 4 * 32768;
    float* b2p = (float*)(imgab + 4 * 16384);
    float* pbuf[2] = {B0, B1};

    prep_kernel<<<512, 256, 0, stream>>>(pi_w1, pi_w2, ii_w1, ii_w2, img1, img2, imgab);
    prep_b2<<<4, 256, 0, stream>>>(pi_b2, b2p);

    for (int d = 0; d < DEPTH; ++d) {
        float* acc = pbuf[d & 1];
        if (d == 0) {
            atom_mlp<16, true><<<N_ATOMS / 4, 256, 0, stream>>>(
                prop, pp0_w1, pp0_b1, pp_w2, pp_b2, res0_w, Hhi, Hlo, acc);
        } else {
            const float* pin = pbuf[(d - 1) & 1];
            atom_mlp<64, false><<<N_ATOMS / 4, 256, 0, stream>>>(
                pin, pp_w1 + (d - 1) * 4096, pp_b1 + (d - 1) * 64,
                pp_w2 + d * 4096, pp_b2 + d * 64, nullptr, Hhi, Hlo, acc);
        }
        pair_kernel<<<512, 512, 0, stream>>>(
            Hhi, Hlo, ind2, basis,
            img1 + d * 16384, img2 + d * 32768, imgab + d * 16384,
            pi_b1 + d * 64, b2p + d * 256, acc);
        out_kernel<<<N_ATOMS / 4, 256, 0, stream>>>(
            acc, out_w1 + d * 4096, out_b1 + d * 64,
            out_w2 + d * 4096, out_b2 + d * 64, out_wo + d * 64,
            out, d == 0 ? 1 : 0);
    }
}